// Round 5
// baseline (268.221 us; speedup 1.0000x reference)
//
#include <hip/hip_runtime.h>

// DIAGNOSTIC ROUND: R2-measured kernel (85.28 us) wrapped in an idempotent
// x8 repeat. Purpose: (a) measure true per-pass kernel cost as
// (dur - 85.3)/7, separating it from the harness's 256 MiB poison fill
// (~44 us) that has hidden vq_fused from every top-5 counter list;
// (b) make vq_fused's dur exceed the fills so rocprof finally reports its
// MfmaUtil/VALUBusy/FETCH_SIZE/LDS_CONFLICT/Occupancy.
// Correctness: each pass recomputes and rewrites identical values.
// Cross-pass hazards: pass p+1 stage writes eh/e2s only after every thread
// passed barrier2(p) (program order), so no reader of pass p can still be
// in the K-loop; pass p+1 pkm writes happen after barrier1(p+1), which
// happens-after epilogue(p) in all threads. The two existing barriers per
// pass are sufficient.

// x (N,S,C,V) = (8,2048,4,64) fp32; embedding (C,K,V) = (4,512,64) fp32.
#define NROW 16384   // N*S
#define CCH  4
#define KCB  512
#define VDIM 64
#define DIAG_REPEAT 8

typedef __attribute__((ext_vector_type(8))) short  short8;   // 8 x bf16
typedef __attribute__((ext_vector_type(4))) float  floatx4;  // MFMA acc

// round-to-nearest-even fp32 -> bf16 bits; rem = v - bf16(v)
__device__ inline unsigned short bf16h(float v, float* rem) {
    unsigned u = __float_as_uint(v);
    unsigned r = u + 0x7FFFu + ((u >> 16) & 1u);
    unsigned short h = (unsigned short)(r >> 16);
    *rem = v - __uint_as_float((unsigned)h << 16);
    return h;
}
__device__ inline unsigned short bf16r(float v) {   // RNE round only
    unsigned u = __float_as_uint(v);
    return (unsigned short)((u + 0x7FFFu + ((u >> 16) & 1u)) >> 16);
}

__global__ __launch_bounds__(512, 4)
void vq_fused(const float* __restrict__ x, const float* __restrict__ emb,
              float* __restrict__ out) {
    extern __shared__ unsigned short smem[];
    unsigned short* eh = smem;              // 32768 ushorts = 64 KB
    float* e2s = (float*)(smem + 32768);    // 512 floats = 2 KB
    float* pkm = e2s + KCB;                 // 128 rows x 2 halves = 1 KB

    const int tid  = threadIdx.x;
    const int lane = tid & 63;
    const int m    = lane & 15;
    const int quad = lane >> 4;
    const int wave = tid >> 6;
    const int c    = blockIdx.y;
    const int blockRow = blockIdx.x * 128;

    const float* embc = emb + (size_t)c * (KCB * VDIM);

#pragma unroll 1
    for (int rep = 0; rep < DIAG_REPEAT; ++rep) {

    // --- stage codebook: wave covers 64 codes; 16 coalesced 1KB wave-reads ---
    {
        const int cb = wave * 64;
        const int koct = m >> 1, half = m & 1;
#pragma unroll
        for (int j = 0; j < 16; ++j) {
            const int g = cb * 16 + j * 64 + lane;       // float4 index
            const float4 t = ((const float4*)embc)[g];
            const int code = cb + j * 4 + quad;          // this lane's code
            ushort4 h4;
            h4.x = bf16r(t.x); h4.y = bf16r(t.y);
            h4.z = bf16r(t.z); h4.w = bf16r(t.w);
            const int off = (koct * 512 + (code ^ koct)) * 8 + half * 4;
            *(ushort4*)&eh[off] = h4;
            // fused exact-fp32 e2: reduce over the 16 lanes of this code
            float s = 0.f;
            s = fmaf(t.x, t.x, s); s = fmaf(t.y, t.y, s);
            s = fmaf(t.z, t.z, s); s = fmaf(t.w, t.w, s);
            s += __shfl_xor(s, 1, 64);
            s += __shfl_xor(s, 2, 64);
            s += __shfl_xor(s, 4, 64);
            s += __shfl_xor(s, 8, 64);
            if (m == 0) e2s[code] = s;
        }
    }

    // --- A fragments: 2 row-groups (32 rows) per wave, 2 k-halves, x hi/lo ---
    const int kh  = wave >> 2;                 // split-K half (code half)
    const int rb2 = blockRow + (wave & 3) * 32;
    short8 ah[2][2], al[2][2];                 // [row-group][k-half]
#pragma unroll
    for (int rg = 0; rg < 2; ++rg) {
        const int row = rb2 + rg * 16 + m;
        const float4* xr = (const float4*)(x + ((size_t)row * CCH + c) * VDIM);
#pragma unroll
        for (int h = 0; h < 2; ++h) {          // k = h*32 + quad*8 + j
            const float4 f0 = xr[h * 8 + quad * 2];
            const float4 f1 = xr[h * 8 + quad * 2 + 1];
            const float fv[8] = {f0.x, f0.y, f0.z, f0.w, f1.x, f1.y, f1.z, f1.w};
            short8 hh, ll;
#pragma unroll
            for (int j = 0; j < 8; ++j) {
                float r, d;
                hh[j] = (short)bf16h(fv[j], &r);
                ll[j] = (short)bf16h(r, &d);
            }
            ah[rg][h] = hh; al[rg][h] = ll;
        }
    }

    __syncthreads();   // barrier 1: eh/e2s ready

    float pk0[4], pk1[4];                      // packed (d,code) per row-group
#pragma unroll
    for (int j = 0; j < 4; ++j) {
        pk0[j] = __uint_as_float(0x7F7FFFFFu);
        pk1[j] = __uint_as_float(0x7F7FFFFFu);
    }

    const int mq0 = m ^ quad;                  // swizzled read indices
    const int mq1 = m ^ (quad + 4);
    const int codeLane = kh * 256 + m;

#pragma unroll 2
    for (int t = 0; t < 16; ++t) {             // 16 tiles (this wave's half)
        const int tt = kh * 16 + t;
        const short8 bh0 = *(const short8*)&eh[( quad      * 512 + tt * 16 + mq0) * 8];
        const short8 bh1 = *(const short8*)&eh[((quad + 4) * 512 + tt * 16 + mq1) * 8];
        const float e2v = e2s[tt * 16 + m];
        const int  code = codeLane + t * 16;   // == tt*16 + m

        floatx4 a0 = {0.f,0.f,0.f,0.f}, a1 = {0.f,0.f,0.f,0.f};
        a0 = __builtin_amdgcn_mfma_f32_16x16x32_bf16(ah[0][0], bh0, a0, 0, 0, 0);
        a1 = __builtin_amdgcn_mfma_f32_16x16x32_bf16(ah[1][0], bh0, a1, 0, 0, 0);
        a0 = __builtin_amdgcn_mfma_f32_16x16x32_bf16(al[0][0], bh0, a0, 0, 0, 0);
        a1 = __builtin_amdgcn_mfma_f32_16x16x32_bf16(al[1][0], bh0, a1, 0, 0, 0);
        a0 = __builtin_amdgcn_mfma_f32_16x16x32_bf16(ah[0][1], bh1, a0, 0, 0, 0);
        a1 = __builtin_amdgcn_mfma_f32_16x16x32_bf16(ah[1][1], bh1, a1, 0, 0, 0);
        a0 = __builtin_amdgcn_mfma_f32_16x16x32_bf16(al[0][1], bh1, a0, 0, 0, 0);
        a1 = __builtin_amdgcn_mfma_f32_16x16x32_bf16(al[1][1], bh1, a1, 0, 0, 0);

#pragma unroll
        for (int j = 0; j < 4; ++j) {
            const float d0 = fmaf(-2.0f, a0[j], e2v);
            pk0[j] = fminf(pk0[j],
                __uint_as_float((__float_as_uint(d0) & 0xFFFFFE00u) | code));
            const float d1 = fmaf(-2.0f, a1[j], e2v);
            pk1[j] = fminf(pk1[j],
                __uint_as_float((__float_as_uint(d1) & 0xFFFFFE00u) | code));
        }
    }

    // within-quad (16-lane) argmin on packed values
#pragma unroll
    for (int j = 0; j < 4; ++j) {
#pragma unroll
        for (int mask = 1; mask < 16; mask <<= 1) {
            pk0[j] = fminf(pk0[j], __shfl_xor(pk0[j], mask, 64));
            pk1[j] = fminf(pk1[j], __shfl_xor(pk1[j], mask, 64));
        }
    }

    // publish per-row winners of this code-half
    {
        const int rloc = (wave & 3) * 32;
#pragma unroll
        for (int j = 0; j < 4; ++j) {
            if (m == j) {
                pkm[(rloc + quad * 4 + j) * 2 + kh]      = pk0[j];
                pkm[(rloc + 16 + quad * 4 + j) * 2 + kh] = pk1[j];
            }
        }
    }

    __syncthreads();   // barrier 2: pkm ready

    // Epilogue: wave handles 16 rows; exact fp32 from original x and emb
    const size_t base1 = (size_t)NROW * CCH * VDIM;
    const size_t base2 = base1 + (size_t)NROW * CCH;
#pragma unroll
    for (int j = 0; j < 4; ++j) {
        const int rl   = wave * 16 + quad * 4 + j;
        const float pmin = fminf(pkm[rl * 2], pkm[rl * 2 + 1]);
        const int  code  = (int)(__float_as_uint(pmin) & 511u);  // uniform in quad
        const int  row   = blockRow + rl;
        const float4 t4 = ((const float4*)(x + ((size_t)row * CCH + c) * VDIM))[m];
        const float4 e4 = ((const float4*)(embc + (size_t)code * VDIM))[m];
        float4 w;
        w.x = (e4.x - t4.x) + t4.x;              // out0 = (output - x) + x
        w.y = (e4.y - t4.y) + t4.y;
        w.z = (e4.z - t4.z) + t4.z;
        w.w = (e4.w - t4.w) + t4.w;
        ((float4*)(out + ((size_t)row * CCH + c) * VDIM))[m] = w;
        float s = 0.f, dx;
        dx = t4.x - e4.x; s = fmaf(dx, dx, s);
        dx = t4.y - e4.y; s = fmaf(dx, dx, s);
        dx = t4.z - e4.z; s = fmaf(dx, dx, s);
        dx = t4.w - e4.w; s = fmaf(dx, dx, s);
        s += __shfl_xor(s, 1, 64);
        s += __shfl_xor(s, 2, 64);
        s += __shfl_xor(s, 4, 64);
        s += __shfl_xor(s, 8, 64);
        if (m == 0) {
            const size_t idx = (size_t)row * CCH + c;
            out[base1 + idx] = s;                // out1
            out[base2 + idx] = s;                // out2 (identical in ref)
        }
    }

    }   // rep loop
}

extern "C" void kernel_launch(void* const* d_in, const int* in_sizes, int n_in,
                              void* d_out, int out_size, void* d_ws, size_t ws_size,
                              hipStream_t stream) {
    const float* x   = (const float*)d_in[0];
    const float* emb = (const float*)d_in[1];
    float* out = (float*)d_out;
    const size_t lds_bytes = 65536u + 2048u + 1024u;   // 68608 B -> 2 blocks/CU
    vq_fused<<<dim3(NROW / 128, CCH), dim3(512), lds_bytes, stream>>>(x, emb, out);
}

// Round 8
// 104.525 us; speedup vs baseline: 2.5661x; 2.5661x over previous
//
#include <hip/hip_runtime.h>

// x (N,S,C,V) = (8,2048,4,64) fp32; embedding (C,K,V) = (4,512,64) fp32.
#define NROW 16384   // N*S
#define CCH  4
#define KCB  512
#define VDIM 64

typedef __attribute__((ext_vector_type(8))) short  short8;   // 8 x bf16
typedef __attribute__((ext_vector_type(4))) float  floatx4;  // MFMA acc / NT ops

// round-to-nearest-even fp32 -> bf16 bits; rem = v - bf16(v)
__device__ inline unsigned short bf16h(float v, float* rem) {
    unsigned u = __float_as_uint(v);
    unsigned r = u + 0x7FFFu + ((u >> 16) & 1u);
    unsigned short h = (unsigned short)(r >> 16);
    *rem = v - __uint_as_float((unsigned)h << 16);
    return h;
}
__device__ inline unsigned short bf16r(float v) {   // RNE round only
    unsigned u = __float_as_uint(v);
    return (unsigned short)((u + 0x7FFFu + ((u >> 16) & 1u)) >> 16);
}
__device__ inline float bf16f(short v) {            // bf16 bits -> fp32
    return __uint_as_float(((unsigned)(unsigned short)v) << 16);
}

// Block = 512 thr (8 waves); grid = (NROW/128, CCH) = 512 blocks = 2/CU.
// LDS = eh (64 KB) + e2 (2 KB) + pkm (1 KB) = 67.5 KB -> 2 blocks/CU.
//
// R5 counters (8-pass diag): per warm pass FETCH 49.6 MB / WRITE 34.3 MB vs
// 34.6 MB compulsory; x was fetched TWICE (build + epilogue re-read, L3 does
// not absorb it) plus ~17 MB store RFO. hbm 3.06 TB/s, MfmaUtil 13%,
// VALUBusy 22%, conflicts 0 -> HBM-traffic-dominated. This version:
//  (1) epilogue reads x_hat from an LDS transpose of the A-fragments
//      (eh is dead after barrier 2; pitch-68-float buffer, bank-uniform),
//      keeping R2's measured full-line out0 store pattern;
//  (2) nontemporal stores for all outputs (kill RFO + write amplification);
//  (3) nontemporal loads for x (read exactly once now).
// NT builtins require clang ext-vector types (floatx4), not HIP float4.
// x_hat = hi+lo bf16 reconstruction; R3 validated identical absmax.
//
// SPLIT-K: waves 0-3 scan codes [0,256), waves 4-7 codes [256,512); both
// halves hold identical A fragments; merge via pkm.
// Packed argmin: pk = min(pk, asfloat((asuint(d) & ~511) | code)); 9 cleared
// mantissa bits perturb d by <~2e-3, inside the accepted bf16-noise band.
// LDS layout eh[(koct*512 + (code ^ koct))*8 + j]: XOR swizzle keeps both
// staging writes and fragment reads bank-conflict-free.
__global__ __launch_bounds__(512, 4)
void vq_fused(const float* __restrict__ x, const float* __restrict__ emb,
              float* __restrict__ out) {
    extern __shared__ unsigned short smem[];
    unsigned short* eh = smem;              // 32768 ushorts = 64 KB
    float* e2s = (float*)(smem + 32768);    // 512 floats = 2 KB
    float* pkm = e2s + KCB;                 // 128 rows x 2 halves = 1 KB

    const int tid  = threadIdx.x;
    const int lane = tid & 63;
    const int m    = lane & 15;
    const int quad = lane >> 4;
    const int wave = tid >> 6;
    const int c    = blockIdx.y;
    const int blockRow = blockIdx.x * 128;

    const float* embc = emb + (size_t)c * (KCB * VDIM);

    // --- stage codebook: wave covers 64 codes; 16 coalesced 1KB wave-reads ---
    {
        const int cb = wave * 64;
        const int koct = m >> 1, half = m & 1;
#pragma unroll
        for (int j = 0; j < 16; ++j) {
            const int g = cb * 16 + j * 64 + lane;       // float4 index
            const float4 t = ((const float4*)embc)[g];
            const int code = cb + j * 4 + quad;          // this lane's code
            ushort4 h4;
            h4.x = bf16r(t.x); h4.y = bf16r(t.y);
            h4.z = bf16r(t.z); h4.w = bf16r(t.w);
            const int off = (koct * 512 + (code ^ koct)) * 8 + half * 4;
            *(ushort4*)&eh[off] = h4;
            // fused exact-fp32 e2: reduce over the 16 lanes of this code
            float s = 0.f;
            s = fmaf(t.x, t.x, s); s = fmaf(t.y, t.y, s);
            s = fmaf(t.z, t.z, s); s = fmaf(t.w, t.w, s);
            s += __shfl_xor(s, 1, 64);
            s += __shfl_xor(s, 2, 64);
            s += __shfl_xor(s, 4, 64);
            s += __shfl_xor(s, 8, 64);
            if (m == 0) e2s[code] = s;
        }
    }

    // --- A fragments: 2 row-groups (32 rows) per wave, 2 k-halves, x hi/lo ---
    const int kh  = wave >> 2;                 // split-K half (code half)
    const int rb2 = blockRow + (wave & 3) * 32;
    short8 ah[2][2], al[2][2];                 // [row-group][k-half]
#pragma unroll
    for (int rg = 0; rg < 2; ++rg) {
        const int row = rb2 + rg * 16 + m;
        const floatx4* xr = (const floatx4*)(x + ((size_t)row * CCH + c) * VDIM);
#pragma unroll
        for (int h = 0; h < 2; ++h) {          // k = h*32 + quad*8 + j
            const floatx4 f0 = __builtin_nontemporal_load(xr + h * 8 + quad * 2);
            const floatx4 f1 = __builtin_nontemporal_load(xr + h * 8 + quad * 2 + 1);
            const float fv[8] = {f0.x, f0.y, f0.z, f0.w, f1.x, f1.y, f1.z, f1.w};
            short8 hh, ll;
#pragma unroll
            for (int j = 0; j < 8; ++j) {
                float r, d;
                hh[j] = (short)bf16h(fv[j], &r);
                ll[j] = (short)bf16h(r, &d);
            }
            ah[rg][h] = hh; al[rg][h] = ll;
        }
    }

    __syncthreads();   // barrier 1: eh/e2s ready

    float pk0[4], pk1[4];                      // packed (d,code) per row-group
#pragma unroll
    for (int j = 0; j < 4; ++j) {
        pk0[j] = __uint_as_float(0x7F7FFFFFu);
        pk1[j] = __uint_as_float(0x7F7FFFFFu);
    }

    const int mq0 = m ^ quad;                  // swizzled read indices
    const int mq1 = m ^ (quad + 4);
    const int codeLane = kh * 256 + m;

#pragma unroll 2
    for (int t = 0; t < 16; ++t) {             // 16 tiles (this wave's half)
        const int tt = kh * 16 + t;
        const short8 bh0 = *(const short8*)&eh[( quad      * 512 + tt * 16 + mq0) * 8];
        const short8 bh1 = *(const short8*)&eh[((quad + 4) * 512 + tt * 16 + mq1) * 8];
        const float e2v = e2s[tt * 16 + m];
        const int  code = codeLane + t * 16;   // == tt*16 + m

        floatx4 a0 = {0.f,0.f,0.f,0.f}, a1 = {0.f,0.f,0.f,0.f};
        a0 = __builtin_amdgcn_mfma_f32_16x16x32_bf16(ah[0][0], bh0, a0, 0, 0, 0);
        a1 = __builtin_amdgcn_mfma_f32_16x16x32_bf16(ah[1][0], bh0, a1, 0, 0, 0);
        a0 = __builtin_amdgcn_mfma_f32_16x16x32_bf16(al[0][0], bh0, a0, 0, 0, 0);
        a1 = __builtin_amdgcn_mfma_f32_16x16x32_bf16(al[1][0], bh0, a1, 0, 0, 0);
        a0 = __builtin_amdgcn_mfma_f32_16x16x32_bf16(ah[0][1], bh1, a0, 0, 0, 0);
        a1 = __builtin_amdgcn_mfma_f32_16x16x32_bf16(ah[1][1], bh1, a1, 0, 0, 0);
        a0 = __builtin_amdgcn_mfma_f32_16x16x32_bf16(al[0][1], bh1, a0, 0, 0, 0);
        a1 = __builtin_amdgcn_mfma_f32_16x16x32_bf16(al[1][1], bh1, a1, 0, 0, 0);

#pragma unroll
        for (int j = 0; j < 4; ++j) {
            const float d0 = fmaf(-2.0f, a0[j], e2v);
            pk0[j] = fminf(pk0[j],
                __uint_as_float((__float_as_uint(d0) & 0xFFFFFE00u) | code));
            const float d1 = fmaf(-2.0f, a1[j], e2v);
            pk1[j] = fminf(pk1[j],
                __uint_as_float((__float_as_uint(d1) & 0xFFFFFE00u) | code));
        }
    }

    // within-quad (16-lane) argmin on packed values
#pragma unroll
    for (int j = 0; j < 4; ++j) {
#pragma unroll
        for (int mask = 1; mask < 16; mask <<= 1) {
            pk0[j] = fminf(pk0[j], __shfl_xor(pk0[j], mask, 64));
            pk1[j] = fminf(pk1[j], __shfl_xor(pk1[j], mask, 64));
        }
    }

    // publish per-row winners of this code-half
    {
        const int rloc = (wave & 3) * 32;
#pragma unroll
        for (int j = 0; j < 4; ++j) {
            if (m == j) {
                pkm[(rloc + quad * 4 + j) * 2 + kh]      = pk0[j];
                pkm[(rloc + 16 + quad * 4 + j) * 2 + kh] = pk1[j];
            }
        }
    }

    __syncthreads();   // barrier 2: pkm ready; eh region now dead

    // --- stash x_hat into LDS transpose buffer (fp32, pitch 68 floats =
    // 17 float4; 128*68*4 = 34816 B, fits in dead eh). Writers: kh==0 waves
    // (both halves hold identical fragments). Bank-uniform both directions.
    {
        floatx4* xs4 = (floatx4*)smem;
        if (kh == 0) {
#pragma unroll
            for (int rg = 0; rg < 2; ++rg) {
                const int lr = (wave & 3) * 32 + rg * 16 + m;
#pragma unroll
                for (int h = 0; h < 2; ++h) {
#pragma unroll
                    for (int hf = 0; hf < 2; ++hf) {
                        floatx4 v;
                        v.x = bf16f(ah[rg][h][hf * 4 + 0]) + bf16f(al[rg][h][hf * 4 + 0]);
                        v.y = bf16f(ah[rg][h][hf * 4 + 1]) + bf16f(al[rg][h][hf * 4 + 1]);
                        v.z = bf16f(ah[rg][h][hf * 4 + 2]) + bf16f(al[rg][h][hf * 4 + 2]);
                        v.w = bf16f(ah[rg][h][hf * 4 + 3]) + bf16f(al[rg][h][hf * 4 + 3]);
                        xs4[lr * 17 + h * 8 + quad * 2 + hf] = v;
                    }
                }
            }
        }
    }

    __syncthreads();   // barrier 3: xs ready

    // Epilogue: wave handles 16 rows; x_hat from LDS, emb from L2; R2's
    // full-line out0 pattern; nontemporal stores (no RFO, no re-read).
    const floatx4* xs4 = (const floatx4*)smem;
    const size_t base1 = (size_t)NROW * CCH * VDIM;
    const size_t base2 = base1 + (size_t)NROW * CCH;
#pragma unroll
    for (int j = 0; j < 4; ++j) {
        const int rl   = wave * 16 + quad * 4 + j;
        const float pmin = fminf(pkm[rl * 2], pkm[rl * 2 + 1]);
        const int  code  = (int)(__float_as_uint(pmin) & 511u);  // uniform in quad
        const int  row   = blockRow + rl;
        const floatx4 t4 = xs4[rl * 17 + m];
        const floatx4 e4 = ((const floatx4*)(embc + (size_t)code * VDIM))[m];
        __builtin_nontemporal_store(
            e4, (floatx4*)(out + ((size_t)row * CCH + c) * VDIM) + m);   // out0
        float s = 0.f, dx;
        dx = t4.x - e4.x; s = fmaf(dx, dx, s);
        dx = t4.y - e4.y; s = fmaf(dx, dx, s);
        dx = t4.z - e4.z; s = fmaf(dx, dx, s);
        dx = t4.w - e4.w; s = fmaf(dx, dx, s);
        s += __shfl_xor(s, 1, 64);
        s += __shfl_xor(s, 2, 64);
        s += __shfl_xor(s, 4, 64);
        s += __shfl_xor(s, 8, 64);
        if (m == 0) {
            const size_t idx = (size_t)row * CCH + c;
            __builtin_nontemporal_store(s, &out[base1 + idx]);   // out1
            __builtin_nontemporal_store(s, &out[base2 + idx]);   // out2
        }
    }
}

extern "C" void kernel_launch(void* const* d_in, const int* in_sizes, int n_in,
                              void* d_out, int out_size, void* d_ws, size_t ws_size,
                              hipStream_t stream) {
    const float* x   = (const float*)d_in[0];
    const float* emb = (const float*)d_in[1];
    float* out = (float*)d_out;
    const size_t lds_bytes = 65536u + 2048u + 1024u;   // 68608 B -> 2 blocks/CU
    vq_fused<<<dim3(NROW / 128, CCH), dim3(512), lds_bytes, stream>>>(x, emb, out);
}

// Round 10
// 88.708 us; speedup vs baseline: 3.0236x; 1.1783x over previous
//
#include <hip/hip_runtime.h>

// x (N,S,C,V) = (8,2048,4,64) fp32; embedding (C,K,V) = (4,512,64) fp32.
#define NROW 16384   // N*S
#define CCH  4
#define KCB  512
#define VDIM 64

typedef __attribute__((ext_vector_type(8))) short  short8;   // 8 x bf16
typedef __attribute__((ext_vector_type(4))) float  floatx4;  // 16B vector

// round-to-nearest-even fp32 -> bf16 bits; rem = v - bf16(v)
__device__ inline unsigned short bf16h(float v, float* rem) {
    unsigned u = __float_as_uint(v);
    unsigned r = u + 0x7FFFu + ((u >> 16) & 1u);
    unsigned short h = (unsigned short)(r >> 16);
    *rem = v - __uint_as_float((unsigned)h << 16);
    return h;
}
__device__ inline unsigned short bf16r(float v) {   // RNE round only
    unsigned u = __float_as_uint(v);
    return (unsigned short)((u + 0x7FFFu + ((u >> 16) & 1u)) >> 16);
}

// ===========================================================================
// Kernel 1: per-(row, channel, code-half) argmin. Grid (128, 4, 2) = 1024
// blocks; 512 thr (8 waves); LDS = 32 KB half-codebook + 1 KB e2 = 33 KB
// -> 4 blocks/CU = 32 waves/CU (2x R8's occupancy; R8 counters showed
// latency-bound: MfmaUtil 6.8%, VALU 20%, hbm 2.7 TB/s, nothing saturated).
// Each wave owns 16 rows x 256 codes (16 tiles, 4 MFMA each); ONE barrier.
// Winner published via atomicMin(uint) with a monotonic float->uint key
// (ws pre-set to 0xFF). Packed (d,code) numerics identical to the proven
// 85.28us kernel: pk = fminf(pk, asfloat((asuint(d)&~511)|code)).
// x loads left cacheable on purpose: k2 re-reads x from L3.
// ===========================================================================
__global__ __launch_bounds__(512, 8)
void vq_argmin(const float* __restrict__ x, const float* __restrict__ emb,
               unsigned int* __restrict__ ws) {
    extern __shared__ unsigned short smem[];
    unsigned short* eh = smem;              // 256 codes x 64 bf16 = 32 KB
    float* e2s = (float*)(smem + 16384);    // 256 floats = 1 KB

    const int tid  = threadIdx.x;
    const int lane = tid & 63;
    const int m    = lane & 15;
    const int quad = lane >> 4;
    const int wave = tid >> 6;
    const int c    = blockIdx.y;
    const int half = blockIdx.z;
    const int blockRow = blockIdx.x * 128;

    const float* embh = emb + ((size_t)c * KCB + (size_t)half * 256) * VDIM;

    // --- stage 256-code half: wave covers 32 codes; 8 coalesced 1KB reads ---
    {
        const int cb = wave * 32;
        const int koct = m >> 1, hlf = m & 1;
#pragma unroll
        for (int j = 0; j < 8; ++j) {
            const int g = cb * 16 + j * 64 + lane;       // float4 index
            const float4 t = ((const float4*)embh)[g];
            const int code = cb + j * 4 + quad;          // local 0..255
            ushort4 h4;
            h4.x = bf16r(t.x); h4.y = bf16r(t.y);
            h4.z = bf16r(t.z); h4.w = bf16r(t.w);
            const int off = (koct * 256 + (code ^ koct)) * 8 + hlf * 4;
            *(ushort4*)&eh[off] = h4;
            // fused exact-fp32 e2 over the 16 lanes of this code
            float s = 0.f;
            s = fmaf(t.x, t.x, s); s = fmaf(t.y, t.y, s);
            s = fmaf(t.z, t.z, s); s = fmaf(t.w, t.w, s);
            s += __shfl_xor(s, 1, 64);
            s += __shfl_xor(s, 2, 64);
            s += __shfl_xor(s, 4, 64);
            s += __shfl_xor(s, 8, 64);
            if (m == 0) e2s[code] = s;
        }
    }

    // --- A fragments: 16 rows/wave, 2 k-halves, x hi/lo bf16 split ---
    short8 ah[2], al[2];
    {
        const int row = blockRow + wave * 16 + m;
        const float4* xr = (const float4*)(x + ((size_t)row * CCH + c) * VDIM);
#pragma unroll
        for (int h = 0; h < 2; ++h) {          // k = h*32 + quad*8 + j
            const float4 f0 = xr[h * 8 + quad * 2];
            const float4 f1 = xr[h * 8 + quad * 2 + 1];
            const float fv[8] = {f0.x, f0.y, f0.z, f0.w, f1.x, f1.y, f1.z, f1.w};
            short8 hh, ll;
#pragma unroll
            for (int j = 0; j < 8; ++j) {
                float r, d;
                hh[j] = (short)bf16h(fv[j], &r);
                ll[j] = (short)bf16h(r, &d);
            }
            ah[h] = hh; al[h] = ll;
        }
    }

    __syncthreads();   // the only barrier: eh/e2s ready

    float pk[4];
#pragma unroll
    for (int j = 0; j < 4; ++j) pk[j] = __uint_as_float(0x7F7FFFFFu);

    const int mq0 = m ^ quad;
    const int mq1 = m ^ (quad + 4);
    const int codeLane = half * 256 + m;

#pragma unroll 2
    for (int t = 0; t < 16; ++t) {             // 16 tiles of 16 codes
        const short8 bh0 = *(const short8*)&eh[( quad      * 256 + t * 16 + mq0) * 8];
        const short8 bh1 = *(const short8*)&eh[((quad + 4) * 256 + t * 16 + mq1) * 8];
        const float e2v = e2s[t * 16 + m];
        const int  code = codeLane + t * 16;   // global code id

        // two independent depth-2 chains (k-half split), summed at use
        floatx4 a0 = {0.f,0.f,0.f,0.f}, a1 = {0.f,0.f,0.f,0.f};
        a0 = __builtin_amdgcn_mfma_f32_16x16x32_bf16(ah[0], bh0, a0, 0, 0, 0);
        a1 = __builtin_amdgcn_mfma_f32_16x16x32_bf16(ah[1], bh1, a1, 0, 0, 0);
        a0 = __builtin_amdgcn_mfma_f32_16x16x32_bf16(al[0], bh0, a0, 0, 0, 0);
        a1 = __builtin_amdgcn_mfma_f32_16x16x32_bf16(al[1], bh1, a1, 0, 0, 0);

#pragma unroll
        for (int j = 0; j < 4; ++j) {
            const float d0 = fmaf(-2.0f, a0[j] + a1[j], e2v);
            pk[j] = fminf(pk[j],
                __uint_as_float((__float_as_uint(d0) & 0xFFFFFE00u) | code));
        }
    }

    // within-quad (16-lane) argmin on packed values
#pragma unroll
    for (int j = 0; j < 4; ++j) {
#pragma unroll
        for (int mask = 1; mask < 16; mask <<= 1)
            pk[j] = fminf(pk[j], __shfl_xor(pk[j], mask, 64));
    }

    // publish: monotonic float->uint key, atomicMin across the 2 halves.
    // key = (u>>31) ? ~u : (u | 0x80000000)  (total order matching float <)
#pragma unroll
    for (int j = 0; j < 4; ++j) {
        if (m == j) {
            const int row = blockRow + wave * 16 + quad * 4 + j;
            const unsigned u = __float_as_uint(pk[j]);
            const unsigned key = (u >> 31) ? ~u : (u | 0x80000000u);
            atomicMin(&ws[row * CCH + c], key);
        }
    }
}

// ===========================================================================
// Kernel 2: streaming epilogue. One wave per row (all 4 channels): x read
// 1KB wave-contiguous (L3-hot from k1), out0 written 1KB wave-contiguous
// (full-line, no RFO -- the fill-kernel store pattern that measures
// 6.1 TB/s with FETCH=14.5KB). Exact fp32 math from original x/emb.
// ===========================================================================
__global__ __launch_bounds__(512)
void vq_epilogue(const float* __restrict__ x, const float* __restrict__ emb,
                 const unsigned int* __restrict__ ws, float* __restrict__ out) {
    const int lane = threadIdx.x & 63;
    const int wave = threadIdx.x >> 6;
    const int row  = blockIdx.x * 8 + wave;
    const int c    = lane >> 4;                // lane*16B == c*256B + m*16B
    const int m    = lane & 15;

    const unsigned key  = ws[row * CCH + c];
    const unsigned code = ((key >> 31) ? key : ~key) & 511u;

    const floatx4 e4 = ((const floatx4*)(emb + ((size_t)c * KCB + code) * VDIM))[m];
    const floatx4 t4 = ((const floatx4*)(x   + (size_t)row * (CCH * VDIM)))[lane];
    ((floatx4*)(out + (size_t)row * (CCH * VDIM)))[lane] = e4;      // out0 = e

    float s = 0.f, dx;
    dx = t4.x - e4.x; s = fmaf(dx, dx, s);
    dx = t4.y - e4.y; s = fmaf(dx, dx, s);
    dx = t4.z - e4.z; s = fmaf(dx, dx, s);
    dx = t4.w - e4.w; s = fmaf(dx, dx, s);
    s += __shfl_xor(s, 1, 64);
    s += __shfl_xor(s, 2, 64);
    s += __shfl_xor(s, 4, 64);
    s += __shfl_xor(s, 8, 64);                 // per-quad (= per-channel) sum

    const float v0 = __shfl(s,  0, 64);
    const float v1 = __shfl(s, 16, 64);
    const float v2 = __shfl(s, 32, 64);
    const float v3 = __shfl(s, 48, 64);
    if (lane == 0) {
        const size_t base1 = (size_t)NROW * CCH * VDIM;
        floatx4 o = {v0, v1, v2, v3};
        *(floatx4*)(out + base1 + (size_t)row * CCH) = o;                       // out1
        *(floatx4*)(out + base1 + (size_t)NROW * CCH + (size_t)row * CCH) = o;  // out2
    }
}

// ===========================================================================
// Fallback (ws unavailable): the proven 85.28us monolithic kernel (R2).
// ===========================================================================
__global__ __launch_bounds__(512, 4)
void vq_mono(const float* __restrict__ x, const float* __restrict__ emb,
             float* __restrict__ out) {
    extern __shared__ unsigned short smem[];
    unsigned short* eh = smem;
    float* e2s = (float*)(smem + 32768);
    float* pkm = e2s + KCB;

    const int tid  = threadIdx.x;
    const int lane = tid & 63;
    const int m    = lane & 15;
    const int quad = lane >> 4;
    const int wave = tid >> 6;
    const int c    = blockIdx.y;
    const int blockRow = blockIdx.x * 128;
    const float* embc = emb + (size_t)c * (KCB * VDIM);

    {
        const int cb = wave * 64;
        const int koct = m >> 1, hlf = m & 1;
#pragma unroll
        for (int j = 0; j < 16; ++j) {
            const int g = cb * 16 + j * 64 + lane;
            const float4 t = ((const float4*)embc)[g];
            const int code = cb + j * 4 + quad;
            ushort4 h4;
            h4.x = bf16r(t.x); h4.y = bf16r(t.y);
            h4.z = bf16r(t.z); h4.w = bf16r(t.w);
            *(ushort4*)&eh[(koct * 512 + (code ^ koct)) * 8 + hlf * 4] = h4;
            float s = 0.f;
            s = fmaf(t.x, t.x, s); s = fmaf(t.y, t.y, s);
            s = fmaf(t.z, t.z, s); s = fmaf(t.w, t.w, s);
            s += __shfl_xor(s, 1, 64); s += __shfl_xor(s, 2, 64);
            s += __shfl_xor(s, 4, 64); s += __shfl_xor(s, 8, 64);
            if (m == 0) e2s[code] = s;
        }
    }
    const int kh  = wave >> 2;
    const int rb2 = blockRow + (wave & 3) * 32;
    short8 ah[2][2], al[2][2];
#pragma unroll
    for (int rg = 0; rg < 2; ++rg) {
        const int row = rb2 + rg * 16 + m;
        const float4* xr = (const float4*)(x + ((size_t)row * CCH + c) * VDIM);
#pragma unroll
        for (int h = 0; h < 2; ++h) {
            const float4 f0 = xr[h * 8 + quad * 2];
            const float4 f1 = xr[h * 8 + quad * 2 + 1];
            const float fv[8] = {f0.x, f0.y, f0.z, f0.w, f1.x, f1.y, f1.z, f1.w};
            short8 hh, ll;
#pragma unroll
            for (int j = 0; j < 8; ++j) {
                float r, d;
                hh[j] = (short)bf16h(fv[j], &r);
                ll[j] = (short)bf16h(r, &d);
            }
            ah[rg][h] = hh; al[rg][h] = ll;
        }
    }
    __syncthreads();
    float pk0[4], pk1[4];
#pragma unroll
    for (int j = 0; j < 4; ++j) {
        pk0[j] = __uint_as_float(0x7F7FFFFFu);
        pk1[j] = __uint_as_float(0x7F7FFFFFu);
    }
    const int mq0 = m ^ quad, mq1 = m ^ (quad + 4);
    const int codeLane = kh * 256 + m;
#pragma unroll 2
    for (int t = 0; t < 16; ++t) {
        const int tt = kh * 16 + t;
        const short8 bh0 = *(const short8*)&eh[( quad      * 512 + tt * 16 + mq0) * 8];
        const short8 bh1 = *(const short8*)&eh[((quad + 4) * 512 + tt * 16 + mq1) * 8];
        const float e2v = e2s[tt * 16 + m];
        const int  code = codeLane + t * 16;
        floatx4 a0 = {0.f,0.f,0.f,0.f}, a1 = {0.f,0.f,0.f,0.f};
        a0 = __builtin_amdgcn_mfma_f32_16x16x32_bf16(ah[0][0], bh0, a0, 0, 0, 0);
        a1 = __builtin_amdgcn_mfma_f32_16x16x32_bf16(ah[1][0], bh0, a1, 0, 0, 0);
        a0 = __builtin_amdgcn_mfma_f32_16x16x32_bf16(al[0][0], bh0, a0, 0, 0, 0);
        a1 = __builtin_amdgcn_mfma_f32_16x16x32_bf16(al[1][0], bh0, a1, 0, 0, 0);
        a0 = __builtin_amdgcn_mfma_f32_16x16x32_bf16(ah[0][1], bh1, a0, 0, 0, 0);
        a1 = __builtin_amdgcn_mfma_f32_16x16x32_bf16(ah[1][1], bh1, a1, 0, 0, 0);
        a0 = __builtin_amdgcn_mfma_f32_16x16x32_bf16(al[0][1], bh1, a0, 0, 0, 0);
        a1 = __builtin_amdgcn_mfma_f32_16x16x32_bf16(al[1][1], bh1, a1, 0, 0, 0);
#pragma unroll
        for (int j = 0; j < 4; ++j) {
            const float d0 = fmaf(-2.0f, a0[j], e2v);
            pk0[j] = fminf(pk0[j], __uint_as_float((__float_as_uint(d0) & 0xFFFFFE00u) | code));
            const float d1 = fmaf(-2.0f, a1[j], e2v);
            pk1[j] = fminf(pk1[j], __uint_as_float((__float_as_uint(d1) & 0xFFFFFE00u) | code));
        }
    }
#pragma unroll
    for (int j = 0; j < 4; ++j) {
#pragma unroll
        for (int mask = 1; mask < 16; mask <<= 1) {
            pk0[j] = fminf(pk0[j], __shfl_xor(pk0[j], mask, 64));
            pk1[j] = fminf(pk1[j], __shfl_xor(pk1[j], mask, 64));
        }
    }
    {
        const int rloc = (wave & 3) * 32;
#pragma unroll
        for (int j = 0; j < 4; ++j) {
            if (m == j) {
                pkm[(rloc + quad * 4 + j) * 2 + kh]      = pk0[j];
                pkm[(rloc + 16 + quad * 4 + j) * 2 + kh] = pk1[j];
            }
        }
    }
    __syncthreads();
    const size_t base1 = (size_t)NROW * CCH * VDIM;
    const size_t base2 = base1 + (size_t)NROW * CCH;
#pragma unroll
    for (int j = 0; j < 4; ++j) {
        const int rl   = wave * 16 + quad * 4 + j;
        const float pmin = fminf(pkm[rl * 2], pkm[rl * 2 + 1]);
        const int  code  = (int)(__float_as_uint(pmin) & 511u);
        const int  row   = blockRow + rl;
        const float4 t4 = ((const float4*)(x + ((size_t)row * CCH + c) * VDIM))[m];
        const float4 e4 = ((const float4*)(embc + (size_t)code * VDIM))[m];
        float4 w;
        w.x = (e4.x - t4.x) + t4.x; w.y = (e4.y - t4.y) + t4.y;
        w.z = (e4.z - t4.z) + t4.z; w.w = (e4.w - t4.w) + t4.w;
        ((float4*)(out + ((size_t)row * CCH + c) * VDIM))[m] = w;
        float s = 0.f, dx;
        dx = t4.x - e4.x; s = fmaf(dx, dx, s);
        dx = t4.y - e4.y; s = fmaf(dx, dx, s);
        dx = t4.z - e4.z; s = fmaf(dx, dx, s);
        dx = t4.w - e4.w; s = fmaf(dx, dx, s);
        s += __shfl_xor(s, 1, 64); s += __shfl_xor(s, 2, 64);
        s += __shfl_xor(s, 4, 64); s += __shfl_xor(s, 8, 64);
        if (m == 0) {
            const size_t idx = (size_t)row * CCH + c;
            out[base1 + idx] = s;
            out[base2 + idx] = s;
        }
    }
}

extern "C" void kernel_launch(void* const* d_in, const int* in_sizes, int n_in,
                              void* d_out, int out_size, void* d_ws, size_t ws_size,
                              hipStream_t stream) {
    const float* x   = (const float*)d_in[0];
    const float* emb = (const float*)d_in[1];
    float* out = (float*)d_out;
    const size_t ws_need = (size_t)NROW * CCH * sizeof(unsigned int);  // 256 KB
    if (d_ws != nullptr && ws_size >= ws_need) {
        unsigned int* ws = (unsigned int*)d_ws;
        hipMemsetAsync(ws, 0xFF, ws_need, stream);                 // key = +inf
        vq_argmin<<<dim3(NROW / 128, CCH, 2), dim3(512),
                    32768u + 1024u, stream>>>(x, emb, ws);         // 33 KB LDS
        vq_epilogue<<<dim3(NROW / 8), dim3(512), 0, stream>>>(x, emb, ws, out);
    } else {
        vq_mono<<<dim3(NROW / 128, CCH), dim3(512),
                  65536u + 2048u + 1024u, stream>>>(x, emb, out);
    }
}